// Round 1
// baseline (471.990 us; speedup 1.0000x reference)
//
#include <hip/hip_runtime.h>

#define FFT_N    8192
#define FFT_LOGN 13
#define BT       512   // threads per block (8 waves)
#define D_IN     2048
#define TWO_PI_OVER_N (6.28318530717958647692f / (float)FFT_N)

__device__ __forceinline__ int br13(int v) {
    return (int)(__brev((unsigned)v) >> (32 - FFT_LOGN));
}

__global__ __launch_bounds__(BT, 4)
void cbp_fused_kernel(const float* __restrict__ x, const float* __restrict__ y,
                      const int* __restrict__ h1, const int* __restrict__ h2,
                      const float* __restrict__ s1, const float* __restrict__ s2,
                      float* __restrict__ out) {
    __shared__ float2 Z[FFT_N];   // 64 KiB
    const int tid = threadIdx.x;
    const int b   = blockIdx.x;

    // ---- zero sketch bins ----
    for (int i = tid; i < FFT_N; i += BT) Z[i] = make_float2(0.f, 0.f);
    __syncthreads();

    // ---- count sketch: z = xs + i*ys (LDS float atomics) ----
    const float* xrow = x + (size_t)b * D_IN;
    const float* yrow = y + (size_t)b * D_IN;
    for (int i = tid; i < D_IN; i += BT) {
        atomicAdd(&Z[h1[i]].x, xrow[i] * s1[i]);
        atomicAdd(&Z[h2[i]].y, yrow[i] * s2[i]);
    }
    __syncthreads();

    // ---- forward FFT, radix-2 DIF (natural in -> bit-reversed out) ----
    for (int lm = FFT_LOGN - 1; lm >= 0; --lm) {
        const int m     = 1 << lm;
        const int shift = (FFT_LOGN - 1) - lm;   // twiddle idx = pos << shift
        for (int j = tid; j < (FFT_N >> 1); j += BT) {
            const int pos = j & (m - 1);
            const int i0  = ((j >> lm) << (lm + 1)) | pos;
            const int i1  = i0 + m;
            float2 a  = Z[i0];
            float2 bb = Z[i1];
            float2 s  = make_float2(a.x + bb.x, a.y + bb.y);
            float2 d  = make_float2(a.x - bb.x, a.y - bb.y);
            float ang = (float)(pos << shift) * (-TWO_PI_OVER_N);
            float sn, cs;
            __sincosf(ang, &sn, &cs);           // (cs,sn) = e^{-i*2pi*twidx/N}
            Z[i0] = s;
            Z[i1] = make_float2(d.x * cs - d.y * sn, d.x * sn + d.y * cs);
        }
        __syncthreads();
    }

    // ---- Hermitian split + pointwise multiply, in bit-reversed storage ----
    // logical k in [1, N/2): pair (k, N-k); k=0 and k=N/2 are real singletons.
    for (int k = tid; k < (FFT_N >> 1); k += BT) {
        if (k == 0) {
            float2 z = Z[0];                    // logical k=0 lives at storage 0
            Z[0] = make_float2(z.x * z.y, 0.f); // Xf[0]=Re, Yf[0]=Im
        } else {
            const int r1 = br13(k);
            const int r2 = br13(FFT_N - k);
            float2 z1 = Z[r1];
            float2 z2 = Z[r2];
            float xr = 0.5f * (z1.x + z2.x);
            float xi = 0.5f * (z1.y - z2.y);
            float yr = 0.5f * (z1.y + z2.y);
            float yi = 0.5f * (z2.x - z1.x);
            float pr = xr * yr - xi * yi;
            float pi = xr * yi + xi * yr;
            Z[r1] = make_float2(pr,  pi);
            Z[r2] = make_float2(pr, -pi);       // P[N-k] = conj(P[k])
        }
    }
    if (tid == 0) {
        const int r = br13(FFT_N >> 1);         // logical k=N/2 -> storage 1
        float2 z = Z[r];
        Z[r] = make_float2(z.x * z.y, 0.f);
    }
    __syncthreads();

    // ---- inverse FFT, radix-2 DIT (bit-reversed in -> natural out) ----
    for (int lm = 0; lm < FFT_LOGN; ++lm) {
        const int m     = 1 << lm;
        const int shift = (FFT_LOGN - 1) - lm;
        for (int j = tid; j < (FFT_N >> 1); j += BT) {
            const int pos = j & (m - 1);
            const int i0  = ((j >> lm) << (lm + 1)) | pos;
            const int i1  = i0 + m;
            float ang = (float)(pos << shift) * (TWO_PI_OVER_N);
            float sn, cs;
            __sincosf(ang, &sn, &cs);           // e^{+i*theta} for inverse
            float2 a  = Z[i0];
            float2 bb = Z[i1];
            float2 t  = make_float2(bb.x * cs - bb.y * sn, bb.x * sn + bb.y * cs);
            Z[i0] = make_float2(a.x + t.x, a.y + t.y);
            Z[i1] = make_float2(a.x - t.x, a.y - t.y);
        }
        __syncthreads();
    }

    // ---- write real part, scaled by 1/N ----
    const float scale = 1.0f / (float)FFT_N;
    float* orow = out + (size_t)b * FFT_N;
    for (int i = tid; i < FFT_N; i += BT) orow[i] = Z[i].x * scale;
}

extern "C" void kernel_launch(void* const* d_in, const int* in_sizes, int n_in,
                              void* d_out, int out_size, void* d_ws, size_t ws_size,
                              hipStream_t stream) {
    const float* x  = (const float*)d_in[0];
    const float* y  = (const float*)d_in[1];
    const int*   h1 = (const int*)d_in[2];
    const int*   h2 = (const int*)d_in[3];
    const float* s1 = (const float*)d_in[4];
    const float* s2 = (const float*)d_in[5];
    float* out = (float*)d_out;

    const int B = in_sizes[0] / D_IN;   // 4096 rows
    cbp_fused_kernel<<<B, BT, 0, stream>>>(x, y, h1, h2, s1, s2, out);
}

// Round 2
// 219.174 us; speedup vs baseline: 2.1535x; 2.1535x over previous
//
#include <hip/hip_runtime.h>

#define FFT_N 8192
#define BT    512
#define D_IN  2048
#define NPAD  8448          // 8192 + 8192/32 pad slots
#define PI2   6.28318530717958647692f

// padded LDS index: +1 float2 per 32 to break power-of-2 bank strides
__device__ __forceinline__ int P(int i) { return i + (i >> 5); }

__device__ __forceinline__ float2 cmulf(float2 a, float2 b) {
    return make_float2(fmaf(-a.y, b.y, a.x * b.x), fmaf(a.y, b.x, a.x * b.y));
}

// 16-point DFT, natural in -> natural out, kernel e^{S*2pi*i*ru/16}, unnormalized.
template<int S>
__device__ __forceinline__ void fft16(float2* v) {
    const float C1 = 0.923879532511286756f;   // cos(pi/8)
    const float C2 = 0.707106781186547524f;   // cos(pi/4)
    const float C3 = 0.382683432365089772f;   // sin(pi/8)
    const float Sf = (float)S;
    float2 t;
#define SW(a,b) t = v[a]; v[a] = v[b]; v[b] = t;
    SW(1,8) SW(2,4) SW(3,12) SW(5,10) SW(7,14) SW(11,13)
#undef SW
#define BF(i0,i1,WR,WI) { float2 w2 = make_float2((WR),(WI)); float2 tt = cmulf(v[i1], w2); \
    v[i1] = make_float2(v[i0].x - tt.x, v[i0].y - tt.y); \
    v[i0] = make_float2(v[i0].x + tt.x, v[i0].y + tt.y); }
#define BF1(i0,i1) { float2 tt = v[i1]; \
    v[i1] = make_float2(v[i0].x - tt.x, v[i0].y - tt.y); \
    v[i0] = make_float2(v[i0].x + tt.x, v[i0].y + tt.y); }
#define BFI(i0,i1) { float2 tt = make_float2(-Sf * v[i1].y, Sf * v[i1].x); \
    v[i1] = make_float2(v[i0].x - tt.x, v[i0].y - tt.y); \
    v[i0] = make_float2(v[i0].x + tt.x, v[i0].y + tt.y); }
    BF1(0,1)  BF1(2,3)  BF1(4,5)   BF1(6,7)  BF1(8,9)  BF1(10,11) BF1(12,13) BF1(14,15)
    BF1(0,2)  BFI(1,3)  BF1(4,6)   BFI(5,7)  BF1(8,10) BFI(9,11)  BF1(12,14) BFI(13,15)
    BF1(0,4)  BF(1,5,C2,Sf*C2) BFI(2,6)  BF(3,7,-C2,Sf*C2)
    BF1(8,12) BF(9,13,C2,Sf*C2) BFI(10,14) BF(11,15,-C2,Sf*C2)
    BF1(0,8)  BF(1,9,C1,Sf*C3)  BF(2,10,C2,Sf*C2)  BF(3,11,C3,Sf*C1)
    BFI(4,12) BF(5,13,-C3,Sf*C1) BF(6,14,-C2,Sf*C2) BF(7,15,-C1,Sf*C3)
#undef BF
#undef BF1
#undef BFI
}

// multiply v[u] by e^{i*ang*u}, u=1..15 (recurrence from one sincos)
__device__ __forceinline__ void twiddle16(float2* v, float ang) {
    float sn, cs;
    __sincosf(ang, &sn, &cs);
    float2 w1 = make_float2(cs, sn);
    float2 w = w1;
    v[1] = cmulf(v[1], w);
    #pragma unroll
    for (int u = 2; u < 16; ++u) { w = cmulf(w, w1); v[u] = cmulf(v[u], w); }
}

__global__ __launch_bounds__(BT, 4)
void cbp_fused_kernel(const float* __restrict__ x, const float* __restrict__ y,
                      const int* __restrict__ h1, const int* __restrict__ h2,
                      const float* __restrict__ s1, const float* __restrict__ s2,
                      float* __restrict__ out) {
    __shared__ float2 Z[NPAD];
    const int tid = threadIdx.x;
    const int b   = blockIdx.x;

    for (int i = tid; i < NPAD; i += BT) Z[i] = make_float2(0.f, 0.f);
    __syncthreads();

    // ---- count sketch: z = xs + i*ys, one float4/int4 per thread ----
    {
        float4 xv  = ((const float4*)(x + (size_t)b * D_IN))[tid];
        float4 yv  = ((const float4*)(y + (size_t)b * D_IN))[tid];
        int4   h1v = ((const int4*)h1)[tid];
        int4   h2v = ((const int4*)h2)[tid];
        float4 s1v = ((const float4*)s1)[tid];
        float4 s2v = ((const float4*)s2)[tid];
        atomicAdd(&Z[P(h1v.x)].x, xv.x * s1v.x);
        atomicAdd(&Z[P(h1v.y)].x, xv.y * s1v.y);
        atomicAdd(&Z[P(h1v.z)].x, xv.z * s1v.z);
        atomicAdd(&Z[P(h1v.w)].x, xv.w * s1v.w);
        atomicAdd(&Z[P(h2v.x)].y, yv.x * s2v.x);
        atomicAdd(&Z[P(h2v.y)].y, yv.y * s2v.y);
        atomicAdd(&Z[P(h2v.z)].y, yv.z * s2v.z);
        atomicAdd(&Z[P(h2v.w)].y, yv.w * s2v.w);
    }
    __syncthreads();

    float2 v[16];

    // ---- forward stage 1: radix-16, stride 512 (per-thread closed set) ----
    {
        const int m = tid;
        #pragma unroll
        for (int r = 0; r < 16; ++r) v[r] = Z[P(m + (r << 9))];
        fft16<-1>(v);
        twiddle16(v, (float)m * (-PI2 / 8192.f));
        #pragma unroll
        for (int u = 0; u < 16; ++u) Z[P((u << 9) + m)] = v[u];
    }
    __syncthreads();

    // ---- forward stage 2: radix-16, stride 32 ----
    {
        const int u1 = tid >> 5, m2 = tid & 31;
        const int base = (u1 << 9) + m2;
        #pragma unroll
        for (int r = 0; r < 16; ++r) v[r] = Z[P(base + (r << 5))];
        fft16<-1>(v);
        twiddle16(v, (float)m2 * (-PI2 / 512.f));
        #pragma unroll
        for (int u = 0; u < 16; ++u) Z[P((u1 << 9) + (u << 5) + m2)] = v[u];
    }
    __syncthreads();

    // ---- forward stage 3 (radix-16) + stage 4 (radix-2 via lane-pair shfl) ----
    {
        const int m3 = tid & 1;
        const int base = ((tid >> 5) << 9) + (((tid >> 1) & 15) << 5) + m3;
        #pragma unroll
        for (int r = 0; r < 16; ++r) v[r] = Z[P(base + (r << 1))];
        fft16<-1>(v);
        twiddle16(v, (float)m3 * (-PI2 / 32.f));
        const float sgn = m3 ? -1.f : 1.f;   // even: v+p ; odd: p-v
        #pragma unroll
        for (int u = 0; u < 16; ++u) {
            float px = __shfl_xor(v[u].x, 1);
            float py = __shfl_xor(v[u].y, 1);
            v[u] = make_float2(fmaf(sgn, v[u].x, px), fmaf(sgn, v[u].y, py));
        }
        #pragma unroll
        for (int u = 0; u < 16; ++u) Z[P(base + (u << 1))] = v[u];
    }
    __syncthreads();

    // ---- Hermitian split + pointwise multiply (digit-reversed storage) ----
    // logical k = d0 + 16*d1 + 256*d2 + 4096*d3 stored at (d0<<9)|(d1<<5)|(d2<<1)|d3
    for (int t = tid; t < 4096; t += BT) {
        if (t == 0) {
            float2 z0 = Z[P(0)];  Z[P(0)] = make_float2(z0.x * z0.y, 0.f);   // k=0
            float2 zh = Z[P(1)];  Z[P(1)] = make_float2(zh.x * zh.y, 0.f);   // k=N/2
        } else {
            const int d2 = t & 15, d1 = (t >> 4) & 15, d0 = (t >> 8) & 15;
            const int k  = d0 + (d1 << 4) + (d2 << 8);     // bijection, k>=1 here
            const int n2 = FFT_N - k;
            const int r1 = (d0 << 9) | (d1 << 5) | (d2 << 1);
            const int r2 = ((n2 & 15) << 9) | (((n2 >> 4) & 15) << 5)
                         | (((n2 >> 8) & 15) << 1) | (n2 >> 12);
            float2 z1 = Z[P(r1)], z2 = Z[P(r2)];
            float xr = 0.5f * (z1.x + z2.x);
            float xi = 0.5f * (z1.y - z2.y);
            float yr = 0.5f * (z1.y + z2.y);
            float yi = 0.5f * (z2.x - z1.x);
            float pr = xr * yr - xi * yi;
            float pi = xr * yi + xi * yr;
            Z[P(r1)] = make_float2(pr,  pi);
            Z[P(r2)] = make_float2(pr, -pi);
        }
    }
    __syncthreads();

    // ---- inverse stage A: radix-2 (shfl) + radix-16, in place ----
    {
        const int m3 = tid & 1;
        const int base = ((tid >> 5) << 9) + (((tid >> 1) & 15) << 5) + m3;
        #pragma unroll
        for (int r = 0; r < 16; ++r) v[r] = Z[P(base + (r << 1))];
        const float sgn = m3 ? -1.f : 1.f;
        #pragma unroll
        for (int u = 0; u < 16; ++u) {
            float px = __shfl_xor(v[u].x, 1);
            float py = __shfl_xor(v[u].y, 1);
            v[u] = make_float2(fmaf(sgn, v[u].x, px), fmaf(sgn, v[u].y, py));
        }
        twiddle16(v, (float)m3 * (PI2 / 32.f));
        fft16<1>(v);
        #pragma unroll
        for (int r = 0; r < 16; ++r) Z[P(base + (r << 1))] = v[r];
    }
    __syncthreads();

    // ---- inverse stage B ----
    {
        const int u1 = tid >> 5, m2 = tid & 31;
        const int gb = (u1 << 9);
        #pragma unroll
        for (int u = 0; u < 16; ++u) v[u] = Z[P(gb + (u << 5) + m2)];
        twiddle16(v, (float)m2 * (PI2 / 512.f));
        fft16<1>(v);
        #pragma unroll
        for (int r = 0; r < 16; ++r) Z[P(gb + m2 + (r << 5))] = v[r];
    }
    __syncthreads();

    // ---- inverse stage C + coalesced global write of real part ----
    {
        const int m = tid;
        #pragma unroll
        for (int u = 0; u < 16; ++u) v[u] = Z[P((u << 9) + m)];
        twiddle16(v, (float)m * (PI2 / 8192.f));
        fft16<1>(v);
        float* orow = out + (size_t)b * FFT_N;
        const float sc = 1.f / (float)FFT_N;
        #pragma unroll
        for (int r = 0; r < 16; ++r) orow[m + (r << 9)] = v[r].x * sc;
    }
}

extern "C" void kernel_launch(void* const* d_in, const int* in_sizes, int n_in,
                              void* d_out, int out_size, void* d_ws, size_t ws_size,
                              hipStream_t stream) {
    const float* x  = (const float*)d_in[0];
    const float* y  = (const float*)d_in[1];
    const int*   h1 = (const int*)d_in[2];
    const int*   h2 = (const int*)d_in[3];
    const float* s1 = (const float*)d_in[4];
    const float* s2 = (const float*)d_in[5];
    float* out = (float*)d_out;

    const int B = in_sizes[0] / D_IN;   // 4096 rows
    cbp_fused_kernel<<<B, BT, 0, stream>>>(x, y, h1, h2, s1, s2, out);
}

// Round 3
// 209.973 us; speedup vs baseline: 2.2479x; 1.0438x over previous
//
#include <hip/hip_runtime.h>

#define FFT_N 8192
#define BT    512
#define D_IN  2048
#define PI2   6.28318530717958647692f

__device__ __forceinline__ float2 cmulf(float2 a, float2 b) {
    return make_float2(fmaf(-a.y, b.y, a.x * b.x), fmaf(a.y, b.x, a.x * b.y));
}

// 16-point DFT, natural in -> natural out, kernel e^{S*2pi*i*ru/16}, unnormalized.
template<int S>
__device__ __forceinline__ void fft16(float2* v) {
    const float C1 = 0.923879532511286756f;   // cos(pi/8)
    const float C2 = 0.707106781186547524f;   // cos(pi/4)
    const float C3 = 0.382683432365089772f;   // sin(pi/8)
    const float Sf = (float)S;
    float2 t;
#define SW(a,b) t = v[a]; v[a] = v[b]; v[b] = t;
    SW(1,8) SW(2,4) SW(3,12) SW(5,10) SW(7,14) SW(11,13)
#undef SW
#define BF(i0,i1,WR,WI) { float2 w2 = make_float2((WR),(WI)); float2 tt = cmulf(v[i1], w2); \
    v[i1] = make_float2(v[i0].x - tt.x, v[i0].y - tt.y); \
    v[i0] = make_float2(v[i0].x + tt.x, v[i0].y + tt.y); }
#define BF1(i0,i1) { float2 tt = v[i1]; \
    v[i1] = make_float2(v[i0].x - tt.x, v[i0].y - tt.y); \
    v[i0] = make_float2(v[i0].x + tt.x, v[i0].y + tt.y); }
#define BFI(i0,i1) { float2 tt = make_float2(-Sf * v[i1].y, Sf * v[i1].x); \
    v[i1] = make_float2(v[i0].x - tt.x, v[i0].y - tt.y); \
    v[i0] = make_float2(v[i0].x + tt.x, v[i0].y + tt.y); }
    BF1(0,1)  BF1(2,3)  BF1(4,5)   BF1(6,7)  BF1(8,9)  BF1(10,11) BF1(12,13) BF1(14,15)
    BF1(0,2)  BFI(1,3)  BF1(4,6)   BFI(5,7)  BF1(8,10) BFI(9,11)  BF1(12,14) BFI(13,15)
    BF1(0,4)  BF(1,5,C2,Sf*C2) BFI(2,6)  BF(3,7,-C2,Sf*C2)
    BF1(8,12) BF(9,13,C2,Sf*C2) BFI(10,14) BF(11,15,-C2,Sf*C2)
    BF1(0,8)  BF(1,9,C1,Sf*C3)  BF(2,10,C2,Sf*C2)  BF(3,11,C3,Sf*C1)
    BFI(4,12) BF(5,13,-C3,Sf*C1) BF(6,14,-C2,Sf*C2) BF(7,15,-C1,Sf*C3)
#undef BF
#undef BF1
#undef BFI
}

// v[u] *= w1^u, u=1..15, log-depth tree from given w1
__device__ __forceinline__ void twiddle16_w(float2* v, float2 w1) {
    float2 w[16];
    w[1] = w1;
    v[1] = cmulf(v[1], w[1]);
    #pragma unroll
    for (int u = 2; u < 16; ++u) {
        w[u] = cmulf(w[u >> 1], w[(u + 1) >> 1]);
        v[u] = cmulf(v[u], w[u]);
    }
}

__device__ __forceinline__ void twiddle16(float2* v, float ang) {
    float sn, cs;
    __sincosf(ang, &sn, &cs);
    twiddle16_w(v, make_float2(cs, sn));
}

__global__ __launch_bounds__(BT, 4)
void cbp_fused_kernel(const float* __restrict__ x, const float* __restrict__ y,
                      const int* __restrict__ h1, const int* __restrict__ h2,
                      const float* __restrict__ s1, const float* __restrict__ s2,
                      float* __restrict__ out) {
    __shared__ float2 Z[8448];                 // 8192 + pads, P(i)=i+(i>>5)
    const int tid = threadIdx.x;
    const int b   = blockIdx.x;

    // ---- zero (float4 stores) ----
    float4* Z4 = (float4*)Z;
    for (int i = tid; i < 4224; i += BT) Z4[i] = make_float4(0.f, 0.f, 0.f, 0.f);
    __syncthreads();

    // ---- count sketch: z = xs + i*ys ----
    {
        float4 xv  = ((const float4*)(x + (size_t)b * D_IN))[tid];
        float4 yv  = ((const float4*)(y + (size_t)b * D_IN))[tid];
        int4   h1v = ((const int4*)h1)[tid];
        int4   h2v = ((const int4*)h2)[tid];
        float4 s1v = ((const float4*)s1)[tid];
        float4 s2v = ((const float4*)s2)[tid];
        atomicAdd(&Z[h1v.x + (h1v.x >> 5)].x, xv.x * s1v.x);
        atomicAdd(&Z[h1v.y + (h1v.y >> 5)].x, xv.y * s1v.y);
        atomicAdd(&Z[h1v.z + (h1v.z >> 5)].x, xv.z * s1v.z);
        atomicAdd(&Z[h1v.w + (h1v.w >> 5)].x, xv.w * s1v.w);
        atomicAdd(&Z[h2v.x + (h2v.x >> 5)].y, yv.x * s2v.x);
        atomicAdd(&Z[h2v.y + (h2v.y >> 5)].y, yv.y * s2v.y);
        atomicAdd(&Z[h2v.z + (h2v.z >> 5)].y, yv.z * s2v.z);
        atomicAdd(&Z[h2v.w + (h2v.w >> 5)].y, yv.w * s2v.w);
    }
    __syncthreads();

    float2 v[16];
    const int u1 = tid >> 5, m2 = tid & 31;            // stage-2 digits
    const int g  = tid >> 5, d1 = (tid >> 1) & 15, m3 = tid & 1;  // stage-3 digits

    // ---- forward stage 1: radix-16, logical stride 512; P-affine stride 528 ----
    {
        float2* zp = &Z[tid + (tid >> 5)];
        #pragma unroll
        for (int r = 0; r < 16; ++r) v[r] = zp[528 * r];
        fft16<-1>(v);
        twiddle16(v, (float)tid * (-PI2 / 8192.f));
        #pragma unroll
        for (int u = 0; u < 16; ++u) zp[528 * u] = v[u];
    }
    __syncthreads();

    // ---- forward stage 2: radix-16, logical stride 32; P-affine stride 33 ----
    {
        float2* zp = &Z[u1 * 528 + m2];
        #pragma unroll
        for (int r = 0; r < 16; ++r) v[r] = zp[33 * r];
        fft16<-1>(v);
        twiddle16(v, (float)m2 * (-PI2 / 512.f));
        #pragma unroll
        for (int u = 0; u < 16; ++u) zp[33 * u] = v[u];
    }
    __syncthreads();

    // ---- forward stage 3 (radix-16, stride 2) + radix-2 via lane-pair shfl ----
    float2* z3p = &Z[g * 528 + d1 * 33 + m3];
    {
        #pragma unroll
        for (int r = 0; r < 16; ++r) v[r] = z3p[2 * r];
        fft16<-1>(v);
        // twiddle w1 = e^{-i*2pi*m3/32}: compile-time constants selected by m3
        float2 w1f = m3 ? make_float2(0.980785280403230449f, -0.195090322016128268f)
                        : make_float2(1.f, 0.f);
        twiddle16_w(v, w1f);
        const float sgn = m3 ? -1.f : 1.f;
        #pragma unroll
        for (int u = 0; u < 16; ++u) {
            float px = __shfl_xor(v[u].x, 1);
            float py = __shfl_xor(v[u].y, 1);
            v[u] = make_float2(fmaf(sgn, v[u].x, px), fmaf(sgn, v[u].y, py));
        }
        #pragma unroll
        for (int u = 0; u < 16; ++u) z3p[2 * u] = v[u];   // publish X4 for partners
    }
    __syncthreads();

    // ---- Hermitian split + pointwise product, in registers ----
    // thread holds k(r) = K0 + 256*r; partner n = 8192 - k has constant low byte e0
    {
        const int K0 = g + (d1 << 4) + (m3 << 12);
        const int e0 = (FFT_N - K0) & 255;
        const int C  = (FFT_N - K0 - e0) >> 8;
        const float2* zb = &Z[(e0 & 15) * 528 + (e0 >> 4) * 33];
        #pragma unroll
        for (int r = 0; r < 16; ++r) {
            const int c = C - r;
            float2 z2 = zb[((c & 15) << 1) + (c >> 4)];
            if (r == 0) { if (K0 == 0) z2 = v[0]; }   // k=0 singleton (tid 0 only)
            float xr = v[r].x + z2.x;                 // 2*Re X
            float xi = v[r].y - z2.y;                 // 2*Im X
            float yr = v[r].y + z2.y;                 // 2*Re Y
            float yi = z2.x - v[r].x;                 // 2*Im Y
            v[r] = make_float2(xr * yr - xi * yi, xr * yi + xi * yr);  // 4*X*Y
        }
    }

    // ---- inverse stage A (regs): radix-2 shfl, twiddle+, fft16<+1> ----
    {
        const float sgn = m3 ? -1.f : 1.f;
        #pragma unroll
        for (int u = 0; u < 16; ++u) {
            float px = __shfl_xor(v[u].x, 1);
            float py = __shfl_xor(v[u].y, 1);
            v[u] = make_float2(fmaf(sgn, v[u].x, px), fmaf(sgn, v[u].y, py));
        }
        float2 w1i = m3 ? make_float2(0.980785280403230449f, 0.195090322016128268f)
                        : make_float2(1.f, 0.f);
        twiddle16_w(v, w1i);
        fft16<1>(v);
    }
    __syncthreads();                         // all partner reads done before overwrite
    {
        #pragma unroll
        for (int r = 0; r < 16; ++r) z3p[2 * r] = v[r];
    }
    __syncthreads();

    // ---- inverse stage B ----
    {
        float2* zp = &Z[u1 * 528 + m2];
        #pragma unroll
        for (int u = 0; u < 16; ++u) v[u] = zp[33 * u];
        twiddle16(v, (float)m2 * (PI2 / 512.f));
        fft16<1>(v);
        #pragma unroll
        for (int r = 0; r < 16; ++r) zp[33 * r] = v[r];
    }
    __syncthreads();

    // ---- inverse stage C + coalesced global write of real part ----
    {
        float2* zp = &Z[tid + (tid >> 5)];
        #pragma unroll
        for (int u = 0; u < 16; ++u) v[u] = zp[528 * u];
        twiddle16(v, (float)tid * (PI2 / 8192.f));
        fft16<1>(v);
        float* orow = out + (size_t)b * FFT_N;
        const float sc = 1.f / (4.f * (float)FFT_N);   // 1/N and the dropped 0.5^2
        #pragma unroll
        for (int r = 0; r < 16; ++r) orow[tid + (r << 9)] = v[r].x * sc;
    }
}

extern "C" void kernel_launch(void* const* d_in, const int* in_sizes, int n_in,
                              void* d_out, int out_size, void* d_ws, size_t ws_size,
                              hipStream_t stream) {
    const float* x  = (const float*)d_in[0];
    const float* y  = (const float*)d_in[1];
    const int*   h1 = (const int*)d_in[2];
    const int*   h2 = (const int*)d_in[3];
    const float* s1 = (const float*)d_in[4];
    const float* s2 = (const float*)d_in[5];
    float* out = (float*)d_out;

    const int B = in_sizes[0] / D_IN;   // 4096 rows
    cbp_fused_kernel<<<B, BT, 0, stream>>>(x, y, h1, h2, s1, s2, out);
}

// Round 4
// 206.770 us; speedup vs baseline: 2.2827x; 1.0155x over previous
//
#include <hip/hip_runtime.h>

#define FFT_N 8192
#define BT    512
#define D_IN  2048
#define PI2   6.28318530717958647692f

typedef float f32x2 __attribute__((ext_vector_type(2)));

__device__ __forceinline__ f32x2 cmul(f32x2 a, f32x2 b) {
    // (a.x*b.x - a.y*b.y, a.x*b.y + a.y*b.x) as packed ops:
    // pk_mul + pk_fma with neg_lo / op_sel-swizzle
    f32x2 q = (f32x2){-a.y, a.y} * (f32x2){b.y, b.x};
    return (f32x2){a.x, a.x} * b + q;
}

// 16-point DFT, natural in -> natural out, kernel e^{S*2pi*i*ru/16}, unnormalized.
template<int S>
__device__ __forceinline__ void fft16(f32x2* v) {
    const float C1 = 0.923879532511286756f;   // cos(pi/8)
    const float C2 = 0.707106781186547524f;   // cos(pi/4)
    const float C3 = 0.382683432365089772f;   // sin(pi/8)
    const float Sf = (float)S;
    f32x2 t;
#define SW(a,b) t = v[a]; v[a] = v[b]; v[b] = t;
    SW(1,8) SW(2,4) SW(3,12) SW(5,10) SW(7,14) SW(11,13)
#undef SW
#define BF(i0,i1,WR,WI) { f32x2 tt = cmul(v[i1], (f32x2){(WR),(WI)}); \
    f32x2 a0 = v[i0]; v[i0] = a0 + tt; v[i1] = a0 - tt; }
#define BF1(i0,i1) { f32x2 tt = v[i1]; \
    f32x2 a0 = v[i0]; v[i0] = a0 + tt; v[i1] = a0 - tt; }
#define BFI(i0,i1) { f32x2 b1 = v[i1]; f32x2 tt = (f32x2){-Sf * b1.y, Sf * b1.x}; \
    f32x2 a0 = v[i0]; v[i0] = a0 + tt; v[i1] = a0 - tt; }
    BF1(0,1)  BF1(2,3)  BF1(4,5)   BF1(6,7)  BF1(8,9)  BF1(10,11) BF1(12,13) BF1(14,15)
    BF1(0,2)  BFI(1,3)  BF1(4,6)   BFI(5,7)  BF1(8,10) BFI(9,11)  BF1(12,14) BFI(13,15)
    BF1(0,4)  BF(1,5,C2,Sf*C2) BFI(2,6)  BF(3,7,-C2,Sf*C2)
    BF1(8,12) BF(9,13,C2,Sf*C2) BFI(10,14) BF(11,15,-C2,Sf*C2)
    BF1(0,8)  BF(1,9,C1,Sf*C3)  BF(2,10,C2,Sf*C2)  BF(3,11,C3,Sf*C1)
    BFI(4,12) BF(5,13,-C3,Sf*C1) BF(6,14,-C2,Sf*C2) BF(7,15,-C1,Sf*C3)
#undef BF
#undef BF1
#undef BFI
}

// v[u] *= w1^u, u=1..15, log-depth tree from given w1
__device__ __forceinline__ void twiddle16_w(f32x2* v, f32x2 w1) {
    f32x2 w[16];
    w[1] = w1;
    v[1] = cmul(v[1], w[1]);
    #pragma unroll
    for (int u = 2; u < 16; ++u) {
        w[u] = cmul(w[u >> 1], w[(u + 1) >> 1]);
        v[u] = cmul(v[u], w[u]);
    }
}

__device__ __forceinline__ void twiddle16(f32x2* v, float ang) {
    float sn, cs;
    __sincosf(ang, &sn, &cs);
    twiddle16_w(v, (f32x2){cs, sn});
}

__global__ __launch_bounds__(BT, 4)
void cbp_fused_kernel(const float* __restrict__ x, const float* __restrict__ y,
                      const int* __restrict__ h1, const int* __restrict__ h2,
                      const float* __restrict__ s1, const float* __restrict__ s2,
                      float* __restrict__ out) {
    __shared__ f32x2 Z[8448];                 // 8192 + pads, P(i)=i+(i>>5)
    const int tid = threadIdx.x;
    const int b   = blockIdx.x;

    // ---- issue global loads first: they hide under the zero phase ----
    float4 xv  = ((const float4*)(x + (size_t)b * D_IN))[tid];
    float4 yv  = ((const float4*)(y + (size_t)b * D_IN))[tid];
    int4   h1v = ((const int4*)h1)[tid];
    int4   h2v = ((const int4*)h2)[tid];
    float4 s1v = ((const float4*)s1)[tid];
    float4 s2v = ((const float4*)s2)[tid];

    // ---- zero (float4 stores) ----
    float4* Z4 = (float4*)Z;
    for (int i = tid; i < 4224; i += BT) Z4[i] = make_float4(0.f, 0.f, 0.f, 0.f);
    __syncthreads();

    // ---- count sketch: z = xs + i*ys ----
    {
        atomicAdd(&((float*)&Z[h1v.x + (h1v.x >> 5)])[0], xv.x * s1v.x);
        atomicAdd(&((float*)&Z[h1v.y + (h1v.y >> 5)])[0], xv.y * s1v.y);
        atomicAdd(&((float*)&Z[h1v.z + (h1v.z >> 5)])[0], xv.z * s1v.z);
        atomicAdd(&((float*)&Z[h1v.w + (h1v.w >> 5)])[0], xv.w * s1v.w);
        atomicAdd(&((float*)&Z[h2v.x + (h2v.x >> 5)])[1], yv.x * s2v.x);
        atomicAdd(&((float*)&Z[h2v.y + (h2v.y >> 5)])[1], yv.y * s2v.y);
        atomicAdd(&((float*)&Z[h2v.z + (h2v.z >> 5)])[1], yv.z * s2v.z);
        atomicAdd(&((float*)&Z[h2v.w + (h2v.w >> 5)])[1], yv.w * s2v.w);
    }
    __syncthreads();

    f32x2 v[16];
    const int u1 = tid >> 5, m2 = tid & 31;            // stage-2 digits
    const int g  = tid >> 5, d1 = (tid >> 1) & 15, m3 = tid & 1;  // stage-3 digits

    // ---- forward stage 1: radix-16, logical stride 512; P-affine stride 528 ----
    {
        f32x2* zp = &Z[tid + (tid >> 5)];
        #pragma unroll
        for (int r = 0; r < 16; ++r) v[r] = zp[528 * r];
        fft16<-1>(v);
        twiddle16(v, (float)tid * (-PI2 / 8192.f));
        #pragma unroll
        for (int u = 0; u < 16; ++u) zp[528 * u] = v[u];
    }
    __syncthreads();

    // ---- forward stage 2: radix-16, logical stride 32; P-affine stride 33 ----
    {
        f32x2* zp = &Z[u1 * 528 + m2];
        #pragma unroll
        for (int r = 0; r < 16; ++r) v[r] = zp[33 * r];
        fft16<-1>(v);
        twiddle16(v, (float)m2 * (-PI2 / 512.f));
        #pragma unroll
        for (int u = 0; u < 16; ++u) zp[33 * u] = v[u];
    }
    __syncthreads();

    // ---- forward stage 3 (radix-16, stride 2) + radix-2 via lane-pair shfl ----
    f32x2* z3p = &Z[g * 528 + d1 * 33 + m3];
    {
        #pragma unroll
        for (int r = 0; r < 16; ++r) v[r] = z3p[2 * r];
        fft16<-1>(v);
        // twiddle w1 = e^{-i*2pi*m3/32}: compile-time constants selected by m3
        f32x2 w1f = m3 ? (f32x2){0.980785280403230449f, -0.195090322016128268f}
                       : (f32x2){1.f, 0.f};
        twiddle16_w(v, w1f);
        const float sgn = m3 ? -1.f : 1.f;
        #pragma unroll
        for (int u = 0; u < 16; ++u) {
            float px = __shfl_xor(v[u].x, 1);
            float py = __shfl_xor(v[u].y, 1);
            v[u] = (f32x2){fmaf(sgn, v[u].x, px), fmaf(sgn, v[u].y, py)};
        }
        #pragma unroll
        for (int u = 0; u < 16; ++u) z3p[2 * u] = v[u];   // publish X4 for partners
    }
    __syncthreads();

    // ---- Hermitian split + pointwise product, in registers ----
    // thread holds k(r) = K0 + 256*r; partner n = 8192 - k has constant low byte e0
    {
        const int K0 = g + (d1 << 4) + (m3 << 12);
        const int e0 = (FFT_N - K0) & 255;
        const int C  = (FFT_N - K0 - e0) >> 8;
        const f32x2* zb = &Z[(e0 & 15) * 528 + (e0 >> 4) * 33];
        #pragma unroll
        for (int r = 0; r < 16; ++r) {
            const int c = C - r;
            f32x2 z2 = zb[((c & 15) << 1) + (c >> 4)];
            if (r == 0) { if (K0 == 0) z2 = v[0]; }   // k=0 singleton (tid 0 only)
            f32x2 X = v[r] + (f32x2){ z2.x, -z2.y};          // (2ReX, 2ImX)
            f32x2 Y = (f32x2){v[r].y, -v[r].x} + (f32x2){z2.y, z2.x};  // (2ReY, 2ImY)
            v[r] = cmul(X, Y);                                // 4*X*Y
        }
    }

    // ---- inverse stage A (regs): radix-2 shfl, twiddle+, fft16<+1> ----
    {
        const float sgn = m3 ? -1.f : 1.f;
        #pragma unroll
        for (int u = 0; u < 16; ++u) {
            float px = __shfl_xor(v[u].x, 1);
            float py = __shfl_xor(v[u].y, 1);
            v[u] = (f32x2){fmaf(sgn, v[u].x, px), fmaf(sgn, v[u].y, py)};
        }
        f32x2 w1i = m3 ? (f32x2){0.980785280403230449f, 0.195090322016128268f}
                       : (f32x2){1.f, 0.f};
        twiddle16_w(v, w1i);
        fft16<1>(v);
    }
    __syncthreads();                         // all partner reads done before overwrite
    {
        #pragma unroll
        for (int r = 0; r < 16; ++r) z3p[2 * r] = v[r];
    }
    __syncthreads();

    // ---- inverse stage B ----
    {
        f32x2* zp = &Z[u1 * 528 + m2];
        #pragma unroll
        for (int u = 0; u < 16; ++u) v[u] = zp[33 * u];
        twiddle16(v, (float)m2 * (PI2 / 512.f));
        fft16<1>(v);
        #pragma unroll
        for (int r = 0; r < 16; ++r) zp[33 * r] = v[r];
    }
    __syncthreads();

    // ---- inverse stage C + coalesced global write of real part ----
    {
        f32x2* zp = &Z[tid + (tid >> 5)];
        #pragma unroll
        for (int u = 0; u < 16; ++u) v[u] = zp[528 * u];
        twiddle16(v, (float)tid * (PI2 / 8192.f));
        fft16<1>(v);
        float* orow = out + (size_t)b * FFT_N;
        const float sc = 1.f / (4.f * (float)FFT_N);   // 1/N and the dropped 0.5^2
        #pragma unroll
        for (int r = 0; r < 16; ++r) orow[tid + (r << 9)] = v[r].x * sc;
    }
}

extern "C" void kernel_launch(void* const* d_in, const int* in_sizes, int n_in,
                              void* d_out, int out_size, void* d_ws, size_t ws_size,
                              hipStream_t stream) {
    const float* x  = (const float*)d_in[0];
    const float* y  = (const float*)d_in[1];
    const int*   h1 = (const int*)d_in[2];
    const int*   h2 = (const int*)d_in[3];
    const float* s1 = (const float*)d_in[4];
    const float* s2 = (const float*)d_in[5];
    float* out = (float*)d_out;

    const int B = in_sizes[0] / D_IN;   // 4096 rows
    cbp_fused_kernel<<<B, BT, 0, stream>>>(x, y, h1, h2, s1, s2, out);
}

// Round 5
// 140.501 us; speedup vs baseline: 3.3593x; 1.4717x over previous
//
#include <hip/hip_runtime.h>

#define FFT_N 8192
#define BT    512
#define D_IN  2048
#define PI2   6.28318530717958647692f

typedef float    f32x2 __attribute__((ext_vector_type(2)));
typedef _Float16 f16x2 __attribute__((ext_vector_type(2)));

// ---- packed-fp16 LDS helpers (compute stays fp32 in regs) ----
__device__ __forceinline__ f32x2 ldH(const unsigned* p) {
    f16x2 h = __builtin_bit_cast(f16x2, *p);
    return (f32x2){(float)h.x, (float)h.y};
}
__device__ __forceinline__ unsigned packH(f32x2 v) {   // round-to-nearest
    f16x2 h = { (_Float16)v.x, (_Float16)v.y };
    return __builtin_bit_cast(unsigned, h);
}
template<int HI>
__device__ __forceinline__ void atomAddH(unsigned* p, float val) {
    unsigned old = *p;
    while (true) {
        f16x2 h = __builtin_bit_cast(f16x2, old);
        if (HI) h.y += (_Float16)val; else h.x += (_Float16)val;
        unsigned nv = __builtin_bit_cast(unsigned, h);
        unsigned got = atomicCAS(p, old, nv);
        if (got == old) break;
        old = got;
    }
}

__device__ __forceinline__ f32x2 cmul(f32x2 a, f32x2 b) {
    f32x2 q = (f32x2){-a.y, a.y} * (f32x2){b.y, b.x};
    return (f32x2){a.x, a.x} * b + q;
}

// 16-point DFT, natural in -> natural out, kernel e^{S*2pi*i*ru/16}, unnormalized.
template<int S>
__device__ __forceinline__ void fft16(f32x2* v) {
    const float C1 = 0.923879532511286756f;
    const float C2 = 0.707106781186547524f;
    const float C3 = 0.382683432365089772f;
    const float Sf = (float)S;
    f32x2 t;
#define SW(a,b) t = v[a]; v[a] = v[b]; v[b] = t;
    SW(1,8) SW(2,4) SW(3,12) SW(5,10) SW(7,14) SW(11,13)
#undef SW
#define BF(i0,i1,WR,WI) { f32x2 tt = cmul(v[i1], (f32x2){(WR),(WI)}); \
    f32x2 a0 = v[i0]; v[i0] = a0 + tt; v[i1] = a0 - tt; }
#define BF1(i0,i1) { f32x2 tt = v[i1]; \
    f32x2 a0 = v[i0]; v[i0] = a0 + tt; v[i1] = a0 - tt; }
#define BFI(i0,i1) { f32x2 b1 = v[i1]; f32x2 tt = (f32x2){-Sf * b1.y, Sf * b1.x}; \
    f32x2 a0 = v[i0]; v[i0] = a0 + tt; v[i1] = a0 - tt; }
    BF1(0,1)  BF1(2,3)  BF1(4,5)   BF1(6,7)  BF1(8,9)  BF1(10,11) BF1(12,13) BF1(14,15)
    BF1(0,2)  BFI(1,3)  BF1(4,6)   BFI(5,7)  BF1(8,10) BFI(9,11)  BF1(12,14) BFI(13,15)
    BF1(0,4)  BF(1,5,C2,Sf*C2) BFI(2,6)  BF(3,7,-C2,Sf*C2)
    BF1(8,12) BF(9,13,C2,Sf*C2) BFI(10,14) BF(11,15,-C2,Sf*C2)
    BF1(0,8)  BF(1,9,C1,Sf*C3)  BF(2,10,C2,Sf*C2)  BF(3,11,C3,Sf*C1)
    BFI(4,12) BF(5,13,-C3,Sf*C1) BF(6,14,-C2,Sf*C2) BF(7,15,-C1,Sf*C3)
#undef BF
#undef BF1
#undef BFI
}

__device__ __forceinline__ void twiddle16_w(f32x2* v, f32x2 w1) {
    f32x2 w[16];
    w[1] = w1;
    v[1] = cmul(v[1], w[1]);
    #pragma unroll
    for (int u = 2; u < 16; ++u) {
        w[u] = cmul(w[u >> 1], w[(u + 1) >> 1]);
        v[u] = cmul(v[u], w[u]);
    }
}
__device__ __forceinline__ void twiddle16(f32x2* v, float ang) {
    float sn, cs;
    __sincosf(ang, &sn, &cs);
    twiddle16_w(v, (f32x2){cs, sn});
}

__global__ __launch_bounds__(BT, 8)   // force VGPR<=64 so 4 blocks/CU fit (LDS 33KB)
void cbp_fused_kernel(const float* __restrict__ x, const float* __restrict__ y,
                      const int* __restrict__ h1, const int* __restrict__ h2,
                      const float* __restrict__ s1, const float* __restrict__ s2,
                      float* __restrict__ out) {
    __shared__ unsigned hz[8448];      // half2-packed complex, pad i+(i>>5); 33792 B
    const int tid = threadIdx.x;
    const int b   = blockIdx.x;

    // hoisted global loads (hide under zero phase)
    float4 xv  = ((const float4*)(x + (size_t)b * D_IN))[tid];
    float4 yv  = ((const float4*)(y + (size_t)b * D_IN))[tid];
    int4   h1v = ((const int4*)h1)[tid];
    int4   h2v = ((const int4*)h2)[tid];
    float4 s1v = ((const float4*)s1)[tid];
    float4 s2v = ((const float4*)s2)[tid];

    // ---- zero (uint4 stores, 2112 of them) ----
    {
        uint4* z4 = (uint4*)hz;
        #pragma unroll
        for (int i = 0; i < 5; ++i) {
            int j = tid + i * BT;
            if (j < 2112) z4[j] = (uint4){0u, 0u, 0u, 0u};
        }
    }
    __syncthreads();

    // ---- count sketch: z = xs + i*ys (fp16 CAS adds) ----
    atomAddH<0>(&hz[h1v.x + (h1v.x >> 5)], xv.x * s1v.x);
    atomAddH<0>(&hz[h1v.y + (h1v.y >> 5)], xv.y * s1v.y);
    atomAddH<0>(&hz[h1v.z + (h1v.z >> 5)], xv.z * s1v.z);
    atomAddH<0>(&hz[h1v.w + (h1v.w >> 5)], xv.w * s1v.w);
    atomAddH<1>(&hz[h2v.x + (h2v.x >> 5)], yv.x * s2v.x);
    atomAddH<1>(&hz[h2v.y + (h2v.y >> 5)], yv.y * s2v.y);
    atomAddH<1>(&hz[h2v.z + (h2v.z >> 5)], yv.z * s2v.z);
    atomAddH<1>(&hz[h2v.w + (h2v.w >> 5)], yv.w * s2v.w);
    __syncthreads();

    f32x2 v[16];
    const int u1 = tid >> 5, m2 = tid & 31;                        // stage-2 digits
    const int g  = tid >> 5, d1 = (tid >> 1) & 15, m3 = tid & 1;   // stage-3 digits

    // ---- forward stage 1: radix-16, logical stride 512 (P-affine stride 528) ----
    {
        unsigned* zp = &hz[tid + (tid >> 5)];
        #pragma unroll
        for (int r = 0; r < 16; ++r) v[r] = ldH(zp + 528 * r);
        fft16<-1>(v);
        twiddle16(v, (float)tid * (-PI2 / 8192.f));
        #pragma unroll
        for (int u = 0; u < 16; ++u) zp[528 * u] = packH(v[u]);
    }
    __syncthreads();

    // ---- forward stage 2: radix-16, logical stride 32 (P-affine stride 33) ----
    {
        unsigned* zp = &hz[u1 * 528 + m2];
        #pragma unroll
        for (int r = 0; r < 16; ++r) v[r] = ldH(zp + 33 * r);
        fft16<-1>(v);
        twiddle16(v, (float)m2 * (-PI2 / 512.f));
        #pragma unroll
        for (int u = 0; u < 16; ++u) zp[33 * u] = packH(v[u]);
    }
    __syncthreads();

    // ---- forward stage 3 (radix-16, stride 2) + radix-2 via lane-pair shfl ----
    unsigned* z3p = &hz[g * 528 + d1 * 33 + m3];
    {
        #pragma unroll
        for (int r = 0; r < 16; ++r) v[r] = ldH(z3p + 2 * r);
        fft16<-1>(v);
        f32x2 w1f = m3 ? (f32x2){0.980785280403230449f, -0.195090322016128268f}
                       : (f32x2){1.f, 0.f};
        twiddle16_w(v, w1f);
        const float sgn = m3 ? -1.f : 1.f;
        #pragma unroll
        for (int u = 0; u < 16; ++u) {
            float px = __shfl_xor(v[u].x, 1);
            float py = __shfl_xor(v[u].y, 1);
            v[u] = (f32x2){fmaf(sgn, v[u].x, px), fmaf(sgn, v[u].y, py)};
        }
        #pragma unroll
        for (int u = 0; u < 16; ++u) z3p[2 * u] = packH(v[u]);   // publish for partners
    }
    __syncthreads();

    // ---- Hermitian split + pointwise product, in registers ----
    {
        const int K0 = g + (d1 << 4) + (m3 << 12);
        const int e0 = (FFT_N - K0) & 255;
        const int C  = (FFT_N - K0 - e0) >> 8;
        const unsigned* zb = &hz[(e0 & 15) * 528 + (e0 >> 4) * 33];
        #pragma unroll
        for (int r = 0; r < 16; ++r) {
            const int c = C - r;
            f32x2 z2 = ldH(zb + ((c & 15) << 1) + (c >> 4));
            if (r == 0) { if (K0 == 0) z2 = v[0]; }   // k=0 singleton (tid 0 only)
            f32x2 X = v[r] + (f32x2){ z2.x, -z2.y};
            f32x2 Y = (f32x2){v[r].y, -v[r].x} + (f32x2){z2.y, z2.x};
            v[r] = cmul(X, Y);                          // 4*X*Y (fp32 regs)
        }
    }

    // ---- inverse stage A (regs): radix-2 shfl, twiddle+, fft16<+1> ----
    {
        const float sgn = m3 ? -1.f : 1.f;
        #pragma unroll
        for (int u = 0; u < 16; ++u) {
            float px = __shfl_xor(v[u].x, 1);
            float py = __shfl_xor(v[u].y, 1);
            v[u] = (f32x2){fmaf(sgn, v[u].x, px), fmaf(sgn, v[u].y, py)};
        }
        f32x2 w1i = m3 ? (f32x2){0.980785280403230449f, 0.195090322016128268f}
                       : (f32x2){1.f, 0.f};
        twiddle16_w(v, w1i);
        fft16<1>(v);
    }
    __syncthreads();                   // partner reads done before overwrite
    {
        #pragma unroll
        for (int r = 0; r < 16; ++r) z3p[2 * r] = packH(v[r] * 0.0625f);  // *2^-4
    }
    __syncthreads();

    // ---- inverse stage B ----
    {
        unsigned* zp = &hz[u1 * 528 + m2];
        #pragma unroll
        for (int u = 0; u < 16; ++u) v[u] = ldH(zp + 33 * u);
        twiddle16(v, (float)m2 * (PI2 / 512.f));
        fft16<1>(v);
        #pragma unroll
        for (int r = 0; r < 16; ++r) zp[33 * r] = packH(v[r] * 0.0625f);  // *2^-4
    }
    __syncthreads();

    // ---- inverse stage C + coalesced global write of real part ----
    {
        unsigned* zp = &hz[tid + (tid >> 5)];
        #pragma unroll
        for (int u = 0; u < 16; ++u) v[u] = ldH(zp + 528 * u);
        twiddle16(v, (float)tid * (PI2 / 8192.f));
        fft16<1>(v);
        float* orow = out + (size_t)b * FFT_N;
        // total scale: 1/(4*8192) * 2^8 (restore the two 2^-4 stage scales) = 2^-7
        const float sc = 0.0078125f;
        #pragma unroll
        for (int r = 0; r < 16; ++r) orow[tid + (r << 9)] = v[r].x * sc;
    }
}

extern "C" void kernel_launch(void* const* d_in, const int* in_sizes, int n_in,
                              void* d_out, int out_size, void* d_ws, size_t ws_size,
                              hipStream_t stream) {
    const float* x  = (const float*)d_in[0];
    const float* y  = (const float*)d_in[1];
    const int*   h1 = (const int*)d_in[2];
    const int*   h2 = (const int*)d_in[3];
    const float* s1 = (const float*)d_in[4];
    const float* s2 = (const float*)d_in[5];
    float* out = (float*)d_out;

    const int B = in_sizes[0] / D_IN;   // 4096 rows
    cbp_fused_kernel<<<B, BT, 0, stream>>>(x, y, h1, h2, s1, s2, out);
}